// Round 1
// 405.659 us; speedup vs baseline: 1.2070x; 1.2070x over previous
//
#include <hip/hip_runtime.h>

#define BB 128
#define CC 768
#define NN 196
#define DD 128
#define KTOP 8
#define MROWS 25088   // B*N

typedef unsigned short u16;
typedef unsigned int u32;

typedef __attribute__((ext_vector_type(8))) short bf16x8;
typedef __attribute__((ext_vector_type(4))) float f32x4;

__device__ __forceinline__ u16 f2bfu(float x) {
    u32 i; __builtin_memcpy(&i, &x, 4);
    u32 r = (i + 0x7fffu + ((i >> 16) & 1u)) >> 16;
    return (u16)r;
}
__device__ __forceinline__ float gelu_f(float x) {
    return 0.5f * x * (1.0f + erff(x * 0.70710678118654752f));
}

// ---------- Kernel 1a: partial[ks][m][d] = feat^T @ Wn (half-K each) -----
// grid (392, 2), block 256. Tile M=64 x N=128, KB=32, 8x4 acc per thread.
__global__ __launch_bounds__(256)
void gemm_node_kernel(const float* __restrict__ feat, const float* __restrict__ Wn,
                      float* __restrict__ part)
{
    __shared__ float As[32][64];    // K-transposed A tile
    __shared__ float Bs[32][DD];
    const int tid = threadIdx.x;
    const int m0  = blockIdx.x * 64;
    const int k0  = blockIdx.y * 384;

    const int r_ld   = tid & 63;
    const int cl_ld  = tid >> 6;         // + 4p
    const int m_ld   = m0 + r_ld;
    const int b_ld   = m_ld / NN;
    const int n_ld   = m_ld % NN;
    const float* fbase = feat + (size_t)b_ld * CC * NN + n_ld;

    const int rg = tid >> 5;             // 8 row-groups of 8 rows
    const int cg = tid & 31;             // 32 col-groups of 4 cols

    float acc[8][4];
#pragma unroll
    for (int i = 0; i < 8; ++i)
#pragma unroll
        for (int j = 0; j < 4; ++j) acc[i][j] = 0.0f;

    for (int kt = 0; kt < 12; ++kt) {
        const int kbase = k0 + kt * 32;
#pragma unroll
        for (int p = 0; p < 8; ++p) {
            const int cl = cl_ld + 4 * p;
            As[cl][r_ld] = fbase[(size_t)(kbase + cl) * NN];
        }
#pragma unroll
        for (int p = 0; p < 4; ++p) {
            const int q = tid + 256 * p;
            const int cl = q >> 5, d4 = (q & 31) * 4;
            *(float4*)(&Bs[cl][d4]) = *(const float4*)(&Wn[(size_t)(kbase + cl) * DD + d4]);
        }
        __syncthreads();
#pragma unroll
        for (int kk = 0; kk < 32; ++kk) {
            const float4 a0 = *(const float4*)(&As[kk][rg * 8]);
            const float4 a1 = *(const float4*)(&As[kk][rg * 8 + 4]);
            const float4 bv = *(const float4*)(&Bs[kk][cg * 4]);
            const float af[8] = {a0.x, a0.y, a0.z, a0.w, a1.x, a1.y, a1.z, a1.w};
#pragma unroll
            for (int i = 0; i < 8; ++i) {
                acc[i][0] += af[i] * bv.x; acc[i][1] += af[i] * bv.y;
                acc[i][2] += af[i] * bv.z; acc[i][3] += af[i] * bv.w;
            }
        }
        __syncthreads();
    }
    float* op = part + ((size_t)blockIdx.y * MROWS + m0 + rg * 8) * DD + cg * 4;
#pragma unroll
    for (int i = 0; i < 8; ++i) {
        *(float4*)(op + (size_t)i * DD) =
            make_float4(acc[i][0], acc[i][1], acc[i][2], acc[i][3]);
    }
}

// ---------- Kernel 1b: nodes = gelu(LN(part0+part1+b)), + inv_norm -------
__global__ __launch_bounds__(128)
void ln_kernel(const float* __restrict__ part, const float* __restrict__ bnode,
               const float* __restrict__ lng, const float* __restrict__ lnb,
               float* __restrict__ nodes, float* __restrict__ inv_norm)
{
    __shared__ float vals[8][DD];
    __shared__ float stats[8][2];
    const int tid = threadIdx.x;
    const int row0 = blockIdx.x * 8;
    const int d = tid;
    const float bb = bnode[d];
#pragma unroll
    for (int r = 0; r < 8; ++r) {
        const size_t m = row0 + r;
        vals[r][d] = part[m * DD + d] + part[(size_t)(MROWS + m) * DD + d] + bb;
    }
    __syncthreads();
    const int lane = tid & 63, wv = tid >> 6;
    for (int r = wv * 4; r < wv * 4 + 4; ++r) {
        float a0 = vals[r][lane], a1 = vals[r][lane + 64];
        float s = a0 + a1;
#pragma unroll
        for (int off = 32; off > 0; off >>= 1) s += __shfl_xor(s, off);
        const float mu = s * (1.0f / 128.0f);
        float d0 = a0 - mu, d1 = a1 - mu;
        float s2 = d0 * d0 + d1 * d1;
#pragma unroll
        for (int off = 32; off > 0; off >>= 1) s2 += __shfl_xor(s2, off);
        if (lane == 0) { stats[r][0] = mu; stats[r][1] = rsqrtf(s2 * (1.0f/128.0f) + 1e-5f); }
    }
    __syncthreads();
    const float g  = lng[d];
    const float be = lnb[d];
    float acc[8];
#pragma unroll
    for (int r = 0; r < 8; ++r) {
        const float y = (vals[r][d] - stats[r][0]) * stats[r][1] * g + be;
        acc[r] = gelu_f(y);
    }
    __syncthreads();
#pragma unroll
    for (int r = 0; r < 8; ++r) vals[r][d] = acc[r] * acc[r];
#pragma unroll
    for (int r = 0; r < 8; ++r) nodes[(size_t)(row0 + r) * DD + d] = acc[r];
    __syncthreads();
    for (int r = wv * 4; r < wv * 4 + 4; ++r) {
        float s = vals[r][lane] + vals[r][lane + 64];
#pragma unroll
        for (int off = 32; off > 0; off >>= 1) s += __shfl_xor(s, off);
        if (lane == 0) inv_norm[row0 + r] = 1.0f / fmaxf(sqrtf(s), 1e-12f);
    }
}

// ------------- Kernel 2: S1 = nodes@We1[0:128], N1 = nodes@We1[128:256] --
__global__ __launch_bounds__(256)
void s1n1_kernel(const float* __restrict__ nodes, const float* __restrict__ We1,
                 float* __restrict__ S1, float* __restrict__ N1)
{
    __shared__ float atile[64][DD];
    const int tid = threadIdx.x;
    const int row0 = blockIdx.x * 64;
#pragma unroll
    for (int p = 0; p < 8; ++p) {
        const int idx = tid + 256 * p;
        const int r = idx >> 5, q = idx & 31;
        *(float4*)(&atile[r][q * 4]) = *(const float4*)(&nodes[(size_t)(row0 + r) * DD + q * 4]);
    }
    __syncthreads();
    const int rg = tid >> 5;
    const int cg = tid & 31;
    const int r0 = rg * 8;
    const int c0 = cg * 8;
    const float* wbase = (c0 < DD) ? (We1 + c0) : (We1 + 128 * DD + (c0 - DD));
    float acc[8][8];
#pragma unroll
    for (int i = 0; i < 8; ++i)
#pragma unroll
        for (int j = 0; j < 8; ++j) acc[i][j] = 0.0f;
    for (int k = 0; k < DD; k += 4) {
        float4 av[8];
#pragma unroll
        for (int ri = 0; ri < 8; ++ri) av[ri] = *(const float4*)(&atile[r0 + ri][k]);
#pragma unroll
        for (int kk = 0; kk < 4; ++kk) {
            const float4 w0 = *(const float4*)(wbase + (size_t)(k + kk) * DD);
            const float4 w1 = *(const float4*)(wbase + (size_t)(k + kk) * DD + 4);
            const float wf[8] = {w0.x, w0.y, w0.z, w0.w, w1.x, w1.y, w1.z, w1.w};
#pragma unroll
            for (int ri = 0; ri < 8; ++ri) {
                const float a = (kk == 0) ? av[ri].x : (kk == 1) ? av[ri].y : (kk == 2) ? av[ri].z : av[ri].w;
#pragma unroll
                for (int ci = 0; ci < 8; ++ci) acc[ri][ci] += a * wf[ci];
            }
        }
    }
    float* outp = (c0 < DD) ? (S1 + (size_t)row0 * DD + c0)
                            : (N1 + (size_t)row0 * DD + (c0 - DD));
#pragma unroll
    for (int ri = 0; ri < 8; ++ri) {
        *(float4*)(outp + (size_t)(r0 + ri) * DD) =
            make_float4(acc[ri][0], acc[ri][1], acc[ri][2], acc[ri][3]);
        *(float4*)(outp + (size_t)(r0 + ri) * DD + 4) =
            make_float4(acc[ri][4], acc[ri][5], acc[ri][6], acc[ri][7]);
    }
}

// --------------- Kernel 3: sim = cosine similarity (fp32!) ---------------
__global__ __launch_bounds__(256)
void sim_kernel(const float* __restrict__ nodes, const float* __restrict__ inv_norm,
                float* __restrict__ sim)
{
    __shared__ float as[28][36];
    __shared__ float bs[NN][36];
    __shared__ float invs[NN];
    const int tid = threadIdx.x;
    const int b  = blockIdx.x / 7;
    const int n0 = (blockIdx.x % 7) * 28;
    const float* nb = nodes + (size_t)b * NN * DD;
    if (tid < NN) invs[tid] = inv_norm[b * NN + tid];
    const bool act = tid < 196;
    const int ai = act ? tid / 28 : 0;
    const int bi = act ? tid % 28 : 0;
    float acc[4][7];
#pragma unroll
    for (int r = 0; r < 4; ++r)
#pragma unroll
        for (int j = 0; j < 7; ++j) acc[r][j] = 0.0f;
    for (int dc = 0; dc < DD; dc += 32) {
        __syncthreads();
        if (tid < 224) {
            const int i = tid >> 3, q = tid & 7;
            *(float4*)(&as[i][q * 4]) = *(const float4*)(&nb[(size_t)(n0 + i) * DD + dc + q * 4]);
        }
        for (int idx = tid; idx < 1568; idx += 256) {
            const int r = idx >> 3, q = idx & 7;
            *(float4*)(&bs[r][q * 4]) = *(const float4*)(&nb[(size_t)r * DD + dc + q * 4]);
        }
        __syncthreads();
        if (act) {
            for (int dd = 0; dd < 32; dd += 4) {
                float4 a4[4], b4[7];
#pragma unroll
                for (int r = 0; r < 4; ++r) a4[r] = *(const float4*)(&as[ai * 4 + r][dd]);
#pragma unroll
                for (int j = 0; j < 7; ++j) b4[j] = *(const float4*)(&bs[bi * 7 + j][dd]);
#pragma unroll
                for (int r = 0; r < 4; ++r)
#pragma unroll
                    for (int j = 0; j < 7; ++j)
                        acc[r][j] += a4[r].x * b4[j].x + a4[r].y * b4[j].y
                                   + a4[r].z * b4[j].z + a4[r].w * b4[j].w;
            }
        }
    }
    if (act) {
#pragma unroll
        for (int r = 0; r < 4; ++r) {
            const int n = n0 + ai * 4 + r;
            const float sn = invs[n];
#pragma unroll
            for (int j = 0; j < 7; ++j) {
                const int m = bi * 7 + j;
                sim[((size_t)b * NN + n) * NN + m] = acc[r][j] * sn * invs[m];
            }
        }
    }
}

// --------------- Kernel 4: top-8 per row (jax tie-break) -----------------
// Extra 32 blocks at the tail pack We2 -> bf16 MFMA-B-fragment order (W2P).
// W2P lives in the inv_norm region, dead after sim_kernel.
__global__ __launch_bounds__(64)
void topk_kernel(const float* __restrict__ sim, int* __restrict__ adj_i,
                 float* __restrict__ adj_o, const float* __restrict__ We2,
                 uint4* __restrict__ W2P)
{
    const int bn = blockIdx.x;
    if (bn >= BB * NN) {
        // ---- We2 fragment packing: entry e = frag*64 + lane ----
        const int e  = (bn - BB * NN) * 64 + threadIdx.x;   // 0..2047
        const int l  = e & 63;
        const int fi = e >> 6;                 // ks*8 + ct
        const int ks = fi >> 3, ct = fi & 7;
        const int k0 = ks * 32 + (l >> 4) * 8;
        const int c  = ct * 16 + (l & 15);
        u16 v[8];
#pragma unroll
        for (int j = 0; j < 8; ++j) v[j] = f2bfu(We2[(size_t)(k0 + j) * DD + c]);
        uint4 pk;
        pk.x = (u32)v[0] | ((u32)v[1] << 16);
        pk.y = (u32)v[2] | ((u32)v[3] << 16);
        pk.z = (u32)v[4] | ((u32)v[5] << 16);
        pk.w = (u32)v[6] | ((u32)v[7] << 16);
        W2P[e] = pk;
        return;
    }
    const int n = bn % NN;
    const int lane = threadIdx.x;
    const float* srow = sim + (size_t)bn * NN;
    float v[4]; int mi[4];
#pragma unroll
    for (int s = 0; s < 4; ++s) {
        const int m = lane + 64 * s;
        mi[s] = m;
        v[s] = (m < NN && m != n) ? srow[m] : -3.0e38f;
    }
    for (int r = 0; r < KTOP; ++r) {
        float bv = v[0]; int bm = mi[0];
#pragma unroll
        for (int s = 1; s < 4; ++s) { if (v[s] > bv) { bv = v[s]; bm = mi[s]; } }
#pragma unroll
        for (int off = 32; off > 0; off >>= 1) {
            const float ov = __shfl_xor(bv, off);
            const int   om = __shfl_xor(bm, off);
            if (ov > bv || (ov == bv && om < bm)) { bv = ov; bm = om; }
        }
        if (lane == 0) {
            adj_i[bn * KTOP + r] = bm;
            adj_o[bn * KTOP + r] = (float)bm;
        }
#pragma unroll
        for (int s = 0; s < 4; ++s) if (mi[s] == bm) v[s] = -3.0e38f;
    }
}

// ------- Kernel 5: displacement table PC[729][D] = posmlp(d)@We1[256:384] --
__global__ __launch_bounds__(128)
void pos_kernel(const float* __restrict__ Wp1, const float* __restrict__ bp1,
                const float* __restrict__ Wp2, const float* __restrict__ bp2,
                const float* __restrict__ We1, float* __restrict__ PC)
{
    __shared__ float t1[64];
    __shared__ float sp[DD];
    const int e = blockIdx.x;
    const int dy = e / 27 - 13, dx = e % 27 - 13;
    const float fy = (float)dy / 13.0f, fx = (float)dx / 13.0f;
    const int tid = threadIdx.x;
    if (tid < 64) {
        const float h = fy * Wp1[tid] + fx * Wp1[64 + tid] + bp1[tid];
        t1[tid] = gelu_f(h);
    }
    __syncthreads();
    float s = bp2[tid];
    for (int j = 0; j < 64; ++j) s += t1[j] * Wp2[j * DD + tid];
    sp[tid] = s;
    __syncthreads();
    float o = 0.0f;
    for (int c = 0; c < DD; ++c) o += sp[c] * We1[(size_t)(256 + c) * DD + tid];
    PC[e * DD + tid] = o;
}

// -------- Kernel 6: edges = gelu(S1+N1g+PCg+be1) @ We2 + be2  (MFMA) -----
// grid B*25 (8 nodes = 64 edge-rows per block), block 256 = 4 waves.
// Wave w owns row-tile [w*16, w*16+16); 8 column tiles of 16; K=128 in 4
// steps of 32 via v_mfma_f32_16x16x32_bf16.
// A-fragments (u = gelu(...)) are computed directly in registers per lane:
//   lane l feeds A row (l&15), k = (l>>4)*8 + j  -- each element once.
// B-fragments come from W2P (pre-packed frag-order bf16) staged to LDS with
// a linear coalesced copy; in-loop ds_read_b128 at lane*16 is conflict-free.
__global__ __launch_bounds__(256)
void edge_kernel(const float* __restrict__ S1, const float* __restrict__ N1,
                 const float* __restrict__ PC, const int* __restrict__ adj_i,
                 const float* __restrict__ be1, const uint4* __restrict__ W2P,
                 const float* __restrict__ be2, float* __restrict__ edges_o)
{
    __shared__ uint4 ldsB[2048];         // 32 KB: [frag(ks*8+ct)][lane] 16B
    const int tid = threadIdx.x;
    const int b  = blockIdx.x / 25;
    const int n0 = (blockIdx.x % 25) * 8;

    // ---- stage B fragments (linear 32 KB copy, conflict-free) ----
#pragma unroll
    for (int p = 0; p < 8; ++p)
        ldsB[tid + 256 * p] = W2P[tid + 256 * p];

    const int l  = tid & 63;
    const int wv = tid >> 6;             // wave = row-tile index
    const int g  = l >> 4;               // k-group within 32-slice
    const int rA = wv * 16 + (l & 15);   // block-local edge row this lane feeds
    const int nA0 = n0 + (rA >> 3);
    const int nA  = (nA0 < NN) ? nA0 : 0;
    const int kA  = rA & 7;
    const int m   = adj_i[((size_t)b * NN + nA) * KTOP + kA];
    const int iy = nA / 14, ix = nA % 14;
    const int my = m / 14,  mx = m % 14;
    const int di = (my - iy + 13) * 27 + (mx - ix + 13);

    const float* s1r = S1 + ((size_t)b * NN + nA) * DD;
    const float* n1r = N1 + ((size_t)b * NN + m) * DD;
    const float* pcr = PC + (size_t)di * DD;

    // ---- A fragments: u = gelu(S1 + N1 + PC + be1), bf16, in-register ----
    bf16x8 afr[4];
#pragma unroll
    for (int ks = 0; ks < 4; ++ks) {
        const int k0 = ks * 32 + g * 8;
        float u[8];
#pragma unroll
        for (int h = 0; h < 2; ++h) {
            const int k = k0 + h * 4;
            const float4 s1 = *(const float4*)(s1r + k);
            const float4 n1 = *(const float4*)(n1r + k);
            const float4 pc = *(const float4*)(pcr + k);
            const float4 b1 = *(const float4*)(be1 + k);
            u[h * 4 + 0] = gelu_f(s1.x + n1.x + pc.x + b1.x);
            u[h * 4 + 1] = gelu_f(s1.y + n1.y + pc.y + b1.y);
            u[h * 4 + 2] = gelu_f(s1.z + n1.z + pc.z + b1.z);
            u[h * 4 + 3] = gelu_f(s1.w + n1.w + pc.w + b1.w);
        }
        bf16x8 a;
#pragma unroll
        for (int j = 0; j < 8; ++j) a[j] = (short)f2bfu(u[j]);
        afr[ks] = a;
    }
    __syncthreads();

    // ---- MFMA: acc[ct] += A(ks) * B(ks,ct) ----
    f32x4 acc[8];
#pragma unroll
    for (int ct = 0; ct < 8; ++ct) {
        f32x4 z = {0.0f, 0.0f, 0.0f, 0.0f};
        acc[ct] = z;
    }
#pragma unroll
    for (int ks = 0; ks < 4; ++ks) {
#pragma unroll
        for (int ct = 0; ct < 8; ++ct) {
            const uint4 bw = ldsB[(ks * 8 + ct) * 64 + l];
            bf16x8 bf; __builtin_memcpy(&bf, &bw, 16);
            acc[ct] = __builtin_amdgcn_mfma_f32_16x16x32_bf16(afr[ks], bf, acc[ct], 0, 0, 0);
        }
    }

    // ---- epilogue: C/D layout col=lane&15, row=(lane>>4)*4+q ----
    const int cl  = l & 15;
    const int rq0 = (l >> 4) * 4;
    float be2f[8];
#pragma unroll
    for (int ct = 0; ct < 8; ++ct) be2f[ct] = be2[ct * 16 + cl];
#pragma unroll
    for (int q = 0; q < 4; ++q) {
        const int r = wv * 16 + rq0 + q;       // block-local row
        const int n = n0 + (r >> 3);
        if (n < NN) {
            float* op = edges_o + (((size_t)b * NN + n) * KTOP + (r & 7)) * DD;
#pragma unroll
            for (int ct = 0; ct < 8; ++ct)
                op[ct * 16 + cl] = acc[ct][q] + be2f[ct];
        }
    }
}

extern "C" void kernel_launch(void* const* d_in, const int* in_sizes, int n_in,
                              void* d_out, int out_size, void* d_ws, size_t ws_size,
                              hipStream_t stream)
{
    const float* feat = (const float*)d_in[0];
    const float* Wn   = (const float*)d_in[1];
    const float* bn   = (const float*)d_in[2];
    const float* lng  = (const float*)d_in[3];
    const float* lnb  = (const float*)d_in[4];
    const float* Wp1  = (const float*)d_in[5];
    const float* bp1  = (const float*)d_in[6];
    const float* Wp2  = (const float*)d_in[7];
    const float* bp2  = (const float*)d_in[8];
    const float* We1  = (const float*)d_in[9];
    const float* be1  = (const float*)d_in[10];
    const float* We2  = (const float*)d_in[11];
    const float* be2  = (const float*)d_in[12];

    float* ws = (float*)d_ws;
    // part (6,422,528 floats) aliases [sim | head of S1] — dead before s1n1/sim run
    float* part     = ws;                    //  0 .. 6,422,528
    float* sim      = ws;                    //  4,917,248
    float* S1       = ws + 4917248;          //  3,211,264
    float* N1       = ws + 8128512;          //  3,211,264
    float* PC       = ws + 11339776;         //     93,312
    float* inv_norm = ws + 11433088;         //     25,088
    int*   adj_i    = (int*)(ws + 11458176); //    200,704 ints
    // W2P (8,192 floats as 2048 uint4) reuses inv_norm region: inv_norm is
    // last read by sim_kernel; W2P is written by topk's tail blocks (after
    // sim on the stream) and read by edge_kernel.
    uint4* W2P      = (uint4*)(ws + 11433088);

    float* out      = (float*)d_out;
    float* nodes    = out;                       // [B,N,D]   fp32
    float* edges_o  = out + 3211264;             // [B,N,K,D] fp32
    float* adj_o    = out + 3211264 + 25690112;  // [B,N,K]   fp32 (int values)

    gemm_node_kernel<<<dim3(392, 2), 256, 0, stream>>>(feat, Wn, part);
    ln_kernel<<<3136, 128, 0, stream>>>(part, bn, lng, lnb, nodes, inv_norm);
    s1n1_kernel<<<392, 256, 0, stream>>>(nodes, We1, S1, N1);
    pos_kernel<<<729, 128, 0, stream>>>(Wp1, bp1, Wp2, bp2, We1, PC);
    sim_kernel<<<BB * 7, 256, 0, stream>>>(nodes, inv_norm, sim);
    topk_kernel<<<BB * NN + 32, 64, 0, stream>>>(sim, adj_i, adj_o, We2, W2P);
    edge_kernel<<<BB * 25, 256, 0, stream>>>(S1, N1, PC, adj_i, be1, W2P, be2, edges_o);
}

// Round 2
// 404.265 us; speedup vs baseline: 1.2111x; 1.0034x over previous
//
#include <hip/hip_runtime.h>

#define BB 128
#define CC 768
#define NN 196
#define DD 128
#define KTOP 8
#define MROWS 25088   // B*N

typedef unsigned short u16;
typedef unsigned int u32;

typedef __attribute__((ext_vector_type(8))) short bf16x8;
typedef __attribute__((ext_vector_type(4))) float f32x4;

__device__ __forceinline__ u16 f2bfu(float x) {
    u32 i; __builtin_memcpy(&i, &x, 4);
    u32 r = (i + 0x7fffu + ((i >> 16) & 1u)) >> 16;
    return (u16)r;
}
__device__ __forceinline__ float bfu2f(u16 h) {
    u32 x = ((u32)h) << 16; float f; __builtin_memcpy(&f, &x, 4); return f;
}
__device__ __forceinline__ void unpack2(u32 u, float& f0, float& f1) {
    u32 lo = u << 16, hi = u & 0xffff0000u;
    __builtin_memcpy(&f0, &lo, 4); __builtin_memcpy(&f1, &hi, 4);
}
__device__ __forceinline__ float gelu_f(float x) {
    return 0.5f * x * (1.0f + erff(x * 0.70710678118654752f));
}

// ---------- Kernel 0: pack We1[0:256] -> bf16 hi/lo MFMA B-fragments -----
// grid 16 x 256. Entry eid = [mat(2)][kc(4)][ct(8)][lane(64)].
// Runs first; output parked in PC region (pos_kernel overwrites later).
__global__ __launch_bounds__(256)
void pack_we1_kernel(const float* __restrict__ We1, uint4* __restrict__ WPH,
                     uint4* __restrict__ WPL)
{
    const int eid = blockIdx.x * 256 + threadIdx.x;   // 0..4095
    const int mat = eid >> 11, rem = eid & 2047;
    const int kc = rem >> 9, ct = (rem >> 6) & 7, l = rem & 63;
    const int g = l >> 4, c = ct * 16 + (l & 15);
    const int krow = mat * 128 + kc * 32 + g * 8;
    u32 h[4], lo[4];
#pragma unroll
    for (int jp = 0; jp < 4; ++jp) {
        const float w0 = We1[(size_t)(krow + 2 * jp) * DD + c];
        const float w1 = We1[(size_t)(krow + 2 * jp + 1) * DD + c];
        const u16 h0 = f2bfu(w0), h1 = f2bfu(w1);
        const u16 l0 = f2bfu(w0 - bfu2f(h0)), l1 = f2bfu(w1 - bfu2f(h1));
        h[jp]  = (u32)h0 | ((u32)h1 << 16);
        lo[jp] = (u32)l0 | ((u32)l1 << 16);
    }
    WPH[eid] = make_uint4(h[0], h[1], h[2], h[3]);
    WPL[eid] = make_uint4(lo[0], lo[1], lo[2], lo[3]);
}

// ---------- Kernel 1a: partial[ks][m][d] = feat^T @ Wn (half-K each) -----
// UNCHANGED: bit-exact fp32 path feeding LN -> nodes -> sim -> topk.
__global__ __launch_bounds__(256)
void gemm_node_kernel(const float* __restrict__ feat, const float* __restrict__ Wn,
                      float* __restrict__ part)
{
    __shared__ float As[32][64];    // K-transposed A tile
    __shared__ float Bs[32][DD];
    const int tid = threadIdx.x;
    const int m0  = blockIdx.x * 64;
    const int k0  = blockIdx.y * 384;

    const int r_ld   = tid & 63;
    const int cl_ld  = tid >> 6;         // + 4p
    const int m_ld   = m0 + r_ld;
    const int b_ld   = m_ld / NN;
    const int n_ld   = m_ld % NN;
    const float* fbase = feat + (size_t)b_ld * CC * NN + n_ld;

    const int rg = tid >> 5;             // 8 row-groups of 8 rows
    const int cg = tid & 31;             // 32 col-groups of 4 cols

    float acc[8][4];
#pragma unroll
    for (int i = 0; i < 8; ++i)
#pragma unroll
        for (int j = 0; j < 4; ++j) acc[i][j] = 0.0f;

    for (int kt = 0; kt < 12; ++kt) {
        const int kbase = k0 + kt * 32;
#pragma unroll
        for (int p = 0; p < 8; ++p) {
            const int cl = cl_ld + 4 * p;
            As[cl][r_ld] = fbase[(size_t)(kbase + cl) * NN];
        }
#pragma unroll
        for (int p = 0; p < 4; ++p) {
            const int q = tid + 256 * p;
            const int cl = q >> 5, d4 = (q & 31) * 4;
            *(float4*)(&Bs[cl][d4]) = *(const float4*)(&Wn[(size_t)(kbase + cl) * DD + d4]);
        }
        __syncthreads();
#pragma unroll
        for (int kk = 0; kk < 32; ++kk) {
            const float4 a0 = *(const float4*)(&As[kk][rg * 8]);
            const float4 a1 = *(const float4*)(&As[kk][rg * 8 + 4]);
            const float4 bv = *(const float4*)(&Bs[kk][cg * 4]);
            const float af[8] = {a0.x, a0.y, a0.z, a0.w, a1.x, a1.y, a1.z, a1.w};
#pragma unroll
            for (int i = 0; i < 8; ++i) {
                acc[i][0] += af[i] * bv.x; acc[i][1] += af[i] * bv.y;
                acc[i][2] += af[i] * bv.z; acc[i][3] += af[i] * bv.w;
            }
        }
        __syncthreads();
    }
    float* op = part + ((size_t)blockIdx.y * MROWS + m0 + rg * 8) * DD + cg * 4;
#pragma unroll
    for (int i = 0; i < 8; ++i) {
        *(float4*)(op + (size_t)i * DD) =
            make_float4(acc[i][0], acc[i][1], acc[i][2], acc[i][3]);
    }
}

// ---------- Kernel 1b: nodes = gelu(LN(part0+part1+b)), + inv_norm -------
__global__ __launch_bounds__(128)
void ln_kernel(const float* __restrict__ part, const float* __restrict__ bnode,
               const float* __restrict__ lng, const float* __restrict__ lnb,
               float* __restrict__ nodes, float* __restrict__ inv_norm)
{
    __shared__ float vals[8][DD];
    __shared__ float stats[8][2];
    const int tid = threadIdx.x;
    const int row0 = blockIdx.x * 8;
    const int d = tid;
    const float bb = bnode[d];
#pragma unroll
    for (int r = 0; r < 8; ++r) {
        const size_t m = row0 + r;
        vals[r][d] = part[m * DD + d] + part[(size_t)(MROWS + m) * DD + d] + bb;
    }
    __syncthreads();
    const int lane = tid & 63, wv = tid >> 6;
    for (int r = wv * 4; r < wv * 4 + 4; ++r) {
        float a0 = vals[r][lane], a1 = vals[r][lane + 64];
        float s = a0 + a1;
#pragma unroll
        for (int off = 32; off > 0; off >>= 1) s += __shfl_xor(s, off);
        const float mu = s * (1.0f / 128.0f);
        float d0 = a0 - mu, d1 = a1 - mu;
        float s2 = d0 * d0 + d1 * d1;
#pragma unroll
        for (int off = 32; off > 0; off >>= 1) s2 += __shfl_xor(s2, off);
        if (lane == 0) { stats[r][0] = mu; stats[r][1] = rsqrtf(s2 * (1.0f/128.0f) + 1e-5f); }
    }
    __syncthreads();
    const float g  = lng[d];
    const float be = lnb[d];
    float acc[8];
#pragma unroll
    for (int r = 0; r < 8; ++r) {
        const float y = (vals[r][d] - stats[r][0]) * stats[r][1] * g + be;
        acc[r] = gelu_f(y);
    }
    __syncthreads();
#pragma unroll
    for (int r = 0; r < 8; ++r) vals[r][d] = acc[r] * acc[r];
#pragma unroll
    for (int r = 0; r < 8; ++r) nodes[(size_t)(row0 + r) * DD + d] = acc[r];
    __syncthreads();
    for (int r = wv * 4; r < wv * 4 + 4; ++r) {
        float s = vals[r][lane] + vals[r][lane + 64];
#pragma unroll
        for (int off = 32; off > 0; off >>= 1) s += __shfl_xor(s, off);
        if (lane == 0) inv_norm[row0 + r] = 1.0f / fmaxf(sqrtf(s), 1e-12f);
    }
}

// ------------- Kernel 2: S1/N1 via MFMA, bf16 hi/lo 3-term split ---------
// grid 392, block 256 = 4 waves. M-tile 64, cols 256 (S1|N1), K=128.
// Wave (wr,wc): rows wr*32 (2 row-tiles), matrix wc (0=S1,1=N1), 8 col-tiles.
// Error ~2^-17 relative: numerically invisible in the edge path.
__global__ __launch_bounds__(256)
void s1n1_kernel(const float* __restrict__ nodes, const uint4* __restrict__ WPH,
                 const uint4* __restrict__ WPL, float* __restrict__ S1,
                 float* __restrict__ N1)
{
    __shared__ uint4 AfH[4][4][64];   // [rt][kc][lane] 16 KB
    __shared__ uint4 AfL[4][4][64];
    const int tid = threadIdx.x;
    const int m0 = blockIdx.x * 64;

    // stage nodes tile 64x128 fp32 -> hi/lo bf16 fragments
#pragma unroll
    for (int p = 0; p < 8; ++p) {
        const int idx = tid + 256 * p;
        const int r = idx >> 5, d0 = (idx & 31) * 4;
        const float4 v = *(const float4*)(&nodes[(size_t)(m0 + r) * DD + d0]);
        const u16 h0 = f2bfu(v.x), h1 = f2bfu(v.y), h2 = f2bfu(v.z), h3 = f2bfu(v.w);
        const u16 l0 = f2bfu(v.x - bfu2f(h0)), l1 = f2bfu(v.y - bfu2f(h1));
        const u16 l2 = f2bfu(v.z - bfu2f(h2)), l3 = f2bfu(v.w - bfu2f(h3));
        const int rt = r >> 4, kc = d0 >> 5;
        const int ln = (((d0 >> 3) & 3) << 4) | (r & 15);
        const int half = (d0 >> 2) & 1;
        u32* ph = (u32*)&AfH[rt][kc][ln];
        u32* pl = (u32*)&AfL[rt][kc][ln];
        ph[half * 2]     = (u32)h0 | ((u32)h1 << 16);
        ph[half * 2 + 1] = (u32)h2 | ((u32)h3 << 16);
        pl[half * 2]     = (u32)l0 | ((u32)l1 << 16);
        pl[half * 2 + 1] = (u32)l2 | ((u32)l3 << 16);
    }
    __syncthreads();

    const int l  = tid & 63;
    const int wv = tid >> 6;
    const int wr = wv >> 1, wc = wv & 1;

    f32x4 acc[2][8];
#pragma unroll
    for (int rt = 0; rt < 2; ++rt)
#pragma unroll
        for (int ct = 0; ct < 8; ++ct) {
            f32x4 z = {0.0f, 0.0f, 0.0f, 0.0f};
            acc[rt][ct] = z;
        }

#pragma unroll
    for (int kc = 0; kc < 4; ++kc) {
        bf16x8 aH[2], aL[2];
#pragma unroll
        for (int rt = 0; rt < 2; ++rt) {
            const uint4 uh = AfH[wr * 2 + rt][kc][l];
            const uint4 ul = AfL[wr * 2 + rt][kc][l];
            __builtin_memcpy(&aH[rt], &uh, 16);
            __builtin_memcpy(&aL[rt], &ul, 16);
        }
#pragma unroll
        for (int ct = 0; ct < 8; ++ct) {
            const uint4 uh = WPH[((wc * 4 + kc) * 8 + ct) * 64 + l];
            const uint4 ul = WPL[((wc * 4 + kc) * 8 + ct) * 64 + l];
            bf16x8 bH, bL;
            __builtin_memcpy(&bH, &uh, 16);
            __builtin_memcpy(&bL, &ul, 16);
#pragma unroll
            for (int rt = 0; rt < 2; ++rt) {
                acc[rt][ct] = __builtin_amdgcn_mfma_f32_16x16x32_bf16(aH[rt], bH, acc[rt][ct], 0, 0, 0);
                acc[rt][ct] = __builtin_amdgcn_mfma_f32_16x16x32_bf16(aL[rt], bH, acc[rt][ct], 0, 0, 0);
                acc[rt][ct] = __builtin_amdgcn_mfma_f32_16x16x32_bf16(aH[rt], bL, acc[rt][ct], 0, 0, 0);
            }
        }
    }

    // epilogue: C/D layout col = l&15, row = (l>>4)*4 + q
    float* outb = wc ? N1 : S1;
    const int cl  = l & 15;
    const int rq0 = (l >> 4) * 4;
#pragma unroll
    for (int rt = 0; rt < 2; ++rt)
#pragma unroll
        for (int q = 0; q < 4; ++q) {
            const size_t row = m0 + wr * 32 + rt * 16 + rq0 + q;
#pragma unroll
            for (int ct = 0; ct < 8; ++ct)
                outb[row * DD + ct * 16 + cl] = acc[rt][ct][q];
        }
}

// --------------- Kernel 3: sim = cosine similarity (fp32!) ---------------
__global__ __launch_bounds__(256)
void sim_kernel(const float* __restrict__ nodes, const float* __restrict__ inv_norm,
                float* __restrict__ sim)
{
    __shared__ float as[28][36];
    __shared__ float bs[NN][36];
    __shared__ float invs[NN];
    const int tid = threadIdx.x;
    const int b  = blockIdx.x / 7;
    const int n0 = (blockIdx.x % 7) * 28;
    const float* nb = nodes + (size_t)b * NN * DD;
    if (tid < NN) invs[tid] = inv_norm[b * NN + tid];
    const bool act = tid < 196;
    const int ai = act ? tid / 28 : 0;
    const int bi = act ? tid % 28 : 0;
    float acc[4][7];
#pragma unroll
    for (int r = 0; r < 4; ++r)
#pragma unroll
        for (int j = 0; j < 7; ++j) acc[r][j] = 0.0f;
    for (int dc = 0; dc < DD; dc += 32) {
        __syncthreads();
        if (tid < 224) {
            const int i = tid >> 3, q = tid & 7;
            *(float4*)(&as[i][q * 4]) = *(const float4*)(&nb[(size_t)(n0 + i) * DD + dc + q * 4]);
        }
        for (int idx = tid; idx < 1568; idx += 256) {
            const int r = idx >> 3, q = idx & 7;
            *(float4*)(&bs[r][q * 4]) = *(const float4*)(&nb[(size_t)r * DD + dc + q * 4]);
        }
        __syncthreads();
        if (act) {
            for (int dd = 0; dd < 32; dd += 4) {
                float4 a4[4], b4[7];
#pragma unroll
                for (int r = 0; r < 4; ++r) a4[r] = *(const float4*)(&as[ai * 4 + r][dd]);
#pragma unroll
                for (int j = 0; j < 7; ++j) b4[j] = *(const float4*)(&bs[bi * 7 + j][dd]);
#pragma unroll
                for (int r = 0; r < 4; ++r)
#pragma unroll
                    for (int j = 0; j < 7; ++j)
                        acc[r][j] += a4[r].x * b4[j].x + a4[r].y * b4[j].y
                                   + a4[r].z * b4[j].z + a4[r].w * b4[j].w;
            }
        }
    }
    if (act) {
#pragma unroll
        for (int r = 0; r < 4; ++r) {
            const int n = n0 + ai * 4 + r;
            const float sn = invs[n];
#pragma unroll
            for (int j = 0; j < 7; ++j) {
                const int m = bi * 7 + j;
                sim[((size_t)b * NN + n) * NN + m] = acc[r][j] * sn * invs[m];
            }
        }
    }
}

// --------------- Kernel 4: top-8, 4 rows/block (bit-identical math) ------
// Tail 8 blocks pack We2 -> bf16 MFMA-B-fragment order (W2P).
__global__ __launch_bounds__(256)
void topk_kernel(const float* __restrict__ sim, int* __restrict__ adj_i,
                 float* __restrict__ adj_o, const float* __restrict__ We2,
                 uint4* __restrict__ W2P)
{
    const int bid = blockIdx.x;
    if (bid >= (BB * NN) / 4) {
        // ---- We2 fragment packing: entry e = frag*64 + lane ----
        const int e  = (bid - (BB * NN) / 4) * 256 + threadIdx.x;   // 0..2047
        const int l  = e & 63;
        const int fi = e >> 6;                 // ks*8 + ct
        const int ks = fi >> 3, ct = fi & 7;
        const int k0 = ks * 32 + (l >> 4) * 8;
        const int c  = ct * 16 + (l & 15);
        u16 v[8];
#pragma unroll
        for (int j = 0; j < 8; ++j) v[j] = f2bfu(We2[(size_t)(k0 + j) * DD + c]);
        uint4 pk;
        pk.x = (u32)v[0] | ((u32)v[1] << 16);
        pk.y = (u32)v[2] | ((u32)v[3] << 16);
        pk.z = (u32)v[4] | ((u32)v[5] << 16);
        pk.w = (u32)v[6] | ((u32)v[7] << 16);
        W2P[e] = pk;
        return;
    }
    const int bn = bid * 4 + (threadIdx.x >> 6);
    const int n = bn % NN;
    const int lane = threadIdx.x & 63;
    const float* srow = sim + (size_t)bn * NN;
    float v[4]; int mi[4];
#pragma unroll
    for (int s = 0; s < 4; ++s) {
        const int m = lane + 64 * s;
        mi[s] = m;
        v[s] = (m < NN && m != n) ? srow[m] : -3.0e38f;
    }
    for (int r = 0; r < KTOP; ++r) {
        float bv = v[0]; int bm = mi[0];
#pragma unroll
        for (int s = 1; s < 4; ++s) { if (v[s] > bv) { bv = v[s]; bm = mi[s]; } }
#pragma unroll
        for (int off = 32; off > 0; off >>= 1) {
            const float ov = __shfl_xor(bv, off);
            const int   om = __shfl_xor(bm, off);
            if (ov > bv || (ov == bv && om < bm)) { bv = ov; bm = om; }
        }
        if (lane == 0) {
            adj_i[bn * KTOP + r] = bm;
            adj_o[bn * KTOP + r] = (float)bm;
        }
#pragma unroll
        for (int s = 0; s < 4; ++s) if (mi[s] == bm) v[s] = -3.0e38f;
    }
}

// ------- Kernel 5: displacement table PC[729][D] = posmlp(d)@We1[256:384] --
__global__ __launch_bounds__(128)
void pos_kernel(const float* __restrict__ Wp1, const float* __restrict__ bp1,
                const float* __restrict__ Wp2, const float* __restrict__ bp2,
                const float* __restrict__ We1, float* __restrict__ PC)
{
    __shared__ float t1[64];
    __shared__ float sp[DD];
    const int e = blockIdx.x;
    const int dy = e / 27 - 13, dx = e % 27 - 13;
    const float fy = (float)dy / 13.0f, fx = (float)dx / 13.0f;
    const int tid = threadIdx.x;
    if (tid < 64) {
        const float h = fy * Wp1[tid] + fx * Wp1[64 + tid] + bp1[tid];
        t1[tid] = gelu_f(h);
    }
    __syncthreads();
    float s = bp2[tid];
    for (int j = 0; j < 64; ++j) s += t1[j] * Wp2[j * DD + tid];
    sp[tid] = s;
    __syncthreads();
    float o = 0.0f;
    for (int c = 0; c < DD; ++c) o += sp[c] * We1[(size_t)(256 + c) * DD + tid];
    PC[e * DD + tid] = o;
}

// -------- Kernel 6: edges = gelu(S1+N1g+PCg+be1) @ We2 + be2  (MFMA) -----
__global__ __launch_bounds__(256)
void edge_kernel(const float* __restrict__ S1, const float* __restrict__ N1,
                 const float* __restrict__ PC, const int* __restrict__ adj_i,
                 const float* __restrict__ be1, const uint4* __restrict__ W2P,
                 const float* __restrict__ be2, float* __restrict__ edges_o)
{
    __shared__ uint4 ldsB[2048];         // 32 KB: [frag(ks*8+ct)][lane] 16B
    const int tid = threadIdx.x;
    const int b  = blockIdx.x / 25;
    const int n0 = (blockIdx.x % 25) * 8;

    // ---- stage B fragments (linear 32 KB copy, conflict-free) ----
#pragma unroll
    for (int p = 0; p < 8; ++p)
        ldsB[tid + 256 * p] = W2P[tid + 256 * p];

    const int l  = tid & 63;
    const int wv = tid >> 6;             // wave = row-tile index
    const int g  = l >> 4;               // k-group within 32-slice
    const int rA = wv * 16 + (l & 15);   // block-local edge row this lane feeds
    const int nA0 = n0 + (rA >> 3);
    const int nA  = (nA0 < NN) ? nA0 : 0;
    const int kA  = rA & 7;
    const int m   = adj_i[((size_t)b * NN + nA) * KTOP + kA];
    const int iy = nA / 14, ix = nA % 14;
    const int my = m / 14,  mx = m % 14;
    const int di = (my - iy + 13) * 27 + (mx - ix + 13);

    const float* s1r = S1 + ((size_t)b * NN + nA) * DD;
    const float* n1r = N1 + ((size_t)b * NN + m) * DD;
    const float* pcr = PC + (size_t)di * DD;

    // ---- A fragments: u = gelu(S1 + N1 + PC + be1), bf16, in-register ----
    bf16x8 afr[4];
#pragma unroll
    for (int ks = 0; ks < 4; ++ks) {
        const int k0 = ks * 32 + g * 8;
        float u[8];
#pragma unroll
        for (int h = 0; h < 2; ++h) {
            const int k = k0 + h * 4;
            const float4 s1 = *(const float4*)(s1r + k);
            const float4 n1 = *(const float4*)(n1r + k);
            const float4 pc = *(const float4*)(pcr + k);
            const float4 b1 = *(const float4*)(be1 + k);
            u[h * 4 + 0] = gelu_f(s1.x + n1.x + pc.x + b1.x);
            u[h * 4 + 1] = gelu_f(s1.y + n1.y + pc.y + b1.y);
            u[h * 4 + 2] = gelu_f(s1.z + n1.z + pc.z + b1.z);
            u[h * 4 + 3] = gelu_f(s1.w + n1.w + pc.w + b1.w);
        }
        bf16x8 a;
#pragma unroll
        for (int j = 0; j < 8; ++j) a[j] = (short)f2bfu(u[j]);
        afr[ks] = a;
    }
    __syncthreads();

    // ---- MFMA: acc[ct] += A(ks) * B(ks,ct) ----
    f32x4 acc[8];
#pragma unroll
    for (int ct = 0; ct < 8; ++ct) {
        f32x4 z = {0.0f, 0.0f, 0.0f, 0.0f};
        acc[ct] = z;
    }
#pragma unroll
    for (int ks = 0; ks < 4; ++ks) {
#pragma unroll
        for (int ct = 0; ct < 8; ++ct) {
            const uint4 bw = ldsB[(ks * 8 + ct) * 64 + l];
            bf16x8 bf; __builtin_memcpy(&bf, &bw, 16);
            acc[ct] = __builtin_amdgcn_mfma_f32_16x16x32_bf16(afr[ks], bf, acc[ct], 0, 0, 0);
        }
    }

    // ---- epilogue: C/D layout col=lane&15, row=(lane>>4)*4+q ----
    const int cl  = l & 15;
    const int rq0 = (l >> 4) * 4;
    float be2f[8];
#pragma unroll
    for (int ct = 0; ct < 8; ++ct) be2f[ct] = be2[ct * 16 + cl];
#pragma unroll
    for (int q = 0; q < 4; ++q) {
        const int r = wv * 16 + rq0 + q;       // block-local row
        const int n = n0 + (r >> 3);
        if (n < NN) {
            float* op = edges_o + (((size_t)b * NN + n) * KTOP + (r & 7)) * DD;
#pragma unroll
            for (int ct = 0; ct < 8; ++ct)
                op[ct * 16 + cl] = acc[ct][q] + be2f[ct];
        }
    }
}

extern "C" void kernel_launch(void* const* d_in, const int* in_sizes, int n_in,
                              void* d_out, int out_size, void* d_ws, size_t ws_size,
                              hipStream_t stream)
{
    const float* feat = (const float*)d_in[0];
    const float* Wn   = (const float*)d_in[1];
    const float* bn   = (const float*)d_in[2];
    const float* lng  = (const float*)d_in[3];
    const float* lnb  = (const float*)d_in[4];
    const float* Wp1  = (const float*)d_in[5];
    const float* bp1  = (const float*)d_in[6];
    const float* Wp2  = (const float*)d_in[7];
    const float* bp2  = (const float*)d_in[8];
    const float* We1  = (const float*)d_in[9];
    const float* be1  = (const float*)d_in[10];
    const float* We2  = (const float*)d_in[11];
    const float* be2  = (const float*)d_in[12];

    float* ws = (float*)d_ws;
    // part (6,422,528 floats) aliases [sim | head of S1] — dead before s1n1/sim run
    float* part     = ws;                    //  0 .. 6,422,528
    float* sim      = ws;                    //  4,917,248
    float* S1       = ws + 4917248;          //  3,211,264
    float* N1       = ws + 8128512;          //  3,211,264
    float* PC       = ws + 11339776;         //     93,312
    float* inv_norm = ws + 11433088;         //     25,088
    int*   adj_i    = (int*)(ws + 11458176); //    200,704 ints
    // W2P (2048 uint4) reuses inv_norm region: inv_norm is last read by
    // sim_kernel; W2P written by topk tail blocks, read by edge_kernel.
    uint4* W2P      = (uint4*)(ws + 11433088);
    // We1 hi/lo fragment packs (4096 uint4 each = 128 KB total) park in the
    // PC region: written by pack_we1 (first launch), read by s1n1, then
    // pos_kernel overwrites PC afterward (stream-ordered).
    uint4* WPH      = (uint4*)(ws + 11339776);
    uint4* WPL      = WPH + 4096;

    float* out      = (float*)d_out;
    float* nodes    = out;                       // [B,N,D]   fp32
    float* edges_o  = out + 3211264;             // [B,N,K,D] fp32
    float* adj_o    = out + 3211264 + 25690112;  // [B,N,K]   fp32 (int values)

    pack_we1_kernel<<<16, 256, 0, stream>>>(We1, WPH, WPL);
    gemm_node_kernel<<<dim3(392, 2), 256, 0, stream>>>(feat, Wn, part);
    ln_kernel<<<3136, 128, 0, stream>>>(part, bn, lng, lnb, nodes, inv_norm);
    s1n1_kernel<<<392, 256, 0, stream>>>(nodes, WPH, WPL, S1, N1);
    pos_kernel<<<729, 128, 0, stream>>>(Wp1, bp1, Wp2, bp2, We1, PC);
    sim_kernel<<<BB * 7, 256, 0, stream>>>(nodes, inv_norm, sim);
    topk_kernel<<<(BB * NN) / 4 + 8, 256, 0, stream>>>(sim, adj_i, adj_o, We2, W2P);
    edge_kernel<<<BB * 25, 256, 0, stream>>>(S1, N1, PC, adj_i, be1, W2P, be2, edges_o);
}

// Round 3
// 392.408 us; speedup vs baseline: 1.2477x; 1.0302x over previous
//
#include <hip/hip_runtime.h>

#define BB 128
#define CC 768
#define NN 196
#define DD 128
#define KTOP 8
#define MROWS 25088   // B*N

typedef unsigned short u16;
typedef unsigned int u32;

typedef __attribute__((ext_vector_type(8))) short bf16x8;
typedef __attribute__((ext_vector_type(4))) float f32x4;

__device__ __forceinline__ u16 f2bfu(float x) {
    u32 i; __builtin_memcpy(&i, &x, 4);
    u32 r = (i + 0x7fffu + ((i >> 16) & 1u)) >> 16;
    return (u16)r;
}
__device__ __forceinline__ float bfu2f(u16 h) {
    u32 x = ((u32)h) << 16; float f; __builtin_memcpy(&f, &x, 4); return f;
}
__device__ __forceinline__ float gelu_f(float x) {
    return 0.5f * x * (1.0f + erff(x * 0.70710678118654752f));
}

// ---------- Kernel 0: pack We1[0:256] -> bf16 hi/lo MFMA B-fragments -----
__global__ __launch_bounds__(256)
void pack_we1_kernel(const float* __restrict__ We1, uint4* __restrict__ WPH,
                     uint4* __restrict__ WPL)
{
    const int eid = blockIdx.x * 256 + threadIdx.x;   // 0..4095
    const int mat = eid >> 11, rem = eid & 2047;
    const int kc = rem >> 9, ct = (rem >> 6) & 7, l = rem & 63;
    const int g = l >> 4, c = ct * 16 + (l & 15);
    const int krow = mat * 128 + kc * 32 + g * 8;
    u32 h[4], lo[4];
#pragma unroll
    for (int jp = 0; jp < 4; ++jp) {
        const float w0 = We1[(size_t)(krow + 2 * jp) * DD + c];
        const float w1 = We1[(size_t)(krow + 2 * jp + 1) * DD + c];
        const u16 h0 = f2bfu(w0), h1 = f2bfu(w1);
        const u16 l0 = f2bfu(w0 - bfu2f(h0)), l1 = f2bfu(w1 - bfu2f(h1));
        h[jp]  = (u32)h0 | ((u32)h1 << 16);
        lo[jp] = (u32)l0 | ((u32)l1 << 16);
    }
    WPH[eid] = make_uint4(h[0], h[1], h[2], h[3]);
    WPL[eid] = make_uint4(lo[0], lo[1], lo[2], lo[3]);
}

// ---------- Kernel 1a: partial[ks][m][d] = feat^T @ Wn (half-K each) -----
// Bit-exact fp32 path (feeds LN -> nodes -> sim -> topk). Same per-output
// accumulation order as the M=64 version; only work granularity changed:
// M-tile 32, 128 threads (2 waves), grid (784,2) = 1568 blocks -> 6.1
// blocks/CU (was 3.06) and a 4x smaller scheduling tail.
__global__ __launch_bounds__(128)
void gemm_node_kernel(const float* __restrict__ feat, const float* __restrict__ Wn,
                      float* __restrict__ part)
{
    __shared__ float As[32][32];    // K-transposed A tile
    __shared__ float Bs[32][DD];
    const int tid = threadIdx.x;
    const int m0  = blockIdx.x * 32;
    const int k0  = blockIdx.y * 384;

    const int r_ld   = tid & 31;
    const int cl_ld  = tid >> 5;         // + 4p
    const int m_ld   = m0 + r_ld;
    const int b_ld   = m_ld / NN;
    const int n_ld   = m_ld % NN;
    const float* fbase = feat + (size_t)b_ld * CC * NN + n_ld;

    const int rg = tid >> 5;             // 4 row-groups of 8 rows
    const int cg = tid & 31;             // 32 col-groups of 4 cols

    float acc[8][4];
#pragma unroll
    for (int i = 0; i < 8; ++i)
#pragma unroll
        for (int j = 0; j < 4; ++j) acc[i][j] = 0.0f;

    for (int kt = 0; kt < 12; ++kt) {
        const int kbase = k0 + kt * 32;
#pragma unroll
        for (int p = 0; p < 8; ++p) {
            const int cl = cl_ld + 4 * p;
            As[cl][r_ld] = fbase[(size_t)(kbase + cl) * NN];
        }
#pragma unroll
        for (int p = 0; p < 8; ++p) {
            const int q = tid + 128 * p;
            const int cl = q >> 5, d4 = (q & 31) * 4;
            *(float4*)(&Bs[cl][d4]) = *(const float4*)(&Wn[(size_t)(kbase + cl) * DD + d4]);
        }
        __syncthreads();
#pragma unroll
        for (int kk = 0; kk < 32; ++kk) {
            const float4 a0 = *(const float4*)(&As[kk][rg * 8]);
            const float4 a1 = *(const float4*)(&As[kk][rg * 8 + 4]);
            const float4 bv = *(const float4*)(&Bs[kk][cg * 4]);
            const float af[8] = {a0.x, a0.y, a0.z, a0.w, a1.x, a1.y, a1.z, a1.w};
#pragma unroll
            for (int i = 0; i < 8; ++i) {
                acc[i][0] += af[i] * bv.x; acc[i][1] += af[i] * bv.y;
                acc[i][2] += af[i] * bv.z; acc[i][3] += af[i] * bv.w;
            }
        }
        __syncthreads();
    }
    float* op = part + ((size_t)blockIdx.y * MROWS + m0 + rg * 8) * DD + cg * 4;
#pragma unroll
    for (int i = 0; i < 8; ++i) {
        *(float4*)(op + (size_t)i * DD) =
            make_float4(acc[i][0], acc[i][1], acc[i][2], acc[i][3]);
    }
}

// ---------- Kernel 1b: nodes = gelu(LN(part0+part1+b)), + inv_norm -------
__global__ __launch_bounds__(128)
void ln_kernel(const float* __restrict__ part, const float* __restrict__ bnode,
               const float* __restrict__ lng, const float* __restrict__ lnb,
               float* __restrict__ nodes, float* __restrict__ inv_norm)
{
    __shared__ float vals[8][DD];
    __shared__ float stats[8][2];
    const int tid = threadIdx.x;
    const int row0 = blockIdx.x * 8;
    const int d = tid;
    const float bb = bnode[d];
#pragma unroll
    for (int r = 0; r < 8; ++r) {
        const size_t m = row0 + r;
        vals[r][d] = part[m * DD + d] + part[(size_t)(MROWS + m) * DD + d] + bb;
    }
    __syncthreads();
    const int lane = tid & 63, wv = tid >> 6;
    for (int r = wv * 4; r < wv * 4 + 4; ++r) {
        float a0 = vals[r][lane], a1 = vals[r][lane + 64];
        float s = a0 + a1;
#pragma unroll
        for (int off = 32; off > 0; off >>= 1) s += __shfl_xor(s, off);
        const float mu = s * (1.0f / 128.0f);
        float d0 = a0 - mu, d1 = a1 - mu;
        float s2 = d0 * d0 + d1 * d1;
#pragma unroll
        for (int off = 32; off > 0; off >>= 1) s2 += __shfl_xor(s2, off);
        if (lane == 0) { stats[r][0] = mu; stats[r][1] = rsqrtf(s2 * (1.0f/128.0f) + 1e-5f); }
    }
    __syncthreads();
    const float g  = lng[d];
    const float be = lnb[d];
    float acc[8];
#pragma unroll
    for (int r = 0; r < 8; ++r) {
        const float y = (vals[r][d] - stats[r][0]) * stats[r][1] * g + be;
        acc[r] = gelu_f(y);
    }
    __syncthreads();
#pragma unroll
    for (int r = 0; r < 8; ++r) vals[r][d] = acc[r] * acc[r];
#pragma unroll
    for (int r = 0; r < 8; ++r) nodes[(size_t)(row0 + r) * DD + d] = acc[r];
    __syncthreads();
    for (int r = wv * 4; r < wv * 4 + 4; ++r) {
        float s = vals[r][lane] + vals[r][lane + 64];
#pragma unroll
        for (int off = 32; off > 0; off >>= 1) s += __shfl_xor(s, off);
        if (lane == 0) inv_norm[row0 + r] = 1.0f / fmaxf(sqrtf(s), 1e-12f);
    }
}

// ------------- Kernel 2: S1/N1 via MFMA, bf16 hi/lo 3-term split ---------
__global__ __launch_bounds__(256)
void s1n1_kernel(const float* __restrict__ nodes, const uint4* __restrict__ WPH,
                 const uint4* __restrict__ WPL, float* __restrict__ S1,
                 float* __restrict__ N1)
{
    __shared__ uint4 AfH[4][4][64];   // [rt][kc][lane] 16 KB
    __shared__ uint4 AfL[4][4][64];
    const int tid = threadIdx.x;
    const int m0 = blockIdx.x * 64;

#pragma unroll
    for (int p = 0; p < 8; ++p) {
        const int idx = tid + 256 * p;
        const int r = idx >> 5, d0 = (idx & 31) * 4;
        const float4 v = *(const float4*)(&nodes[(size_t)(m0 + r) * DD + d0]);
        const u16 h0 = f2bfu(v.x), h1 = f2bfu(v.y), h2 = f2bfu(v.z), h3 = f2bfu(v.w);
        const u16 l0 = f2bfu(v.x - bfu2f(h0)), l1 = f2bfu(v.y - bfu2f(h1));
        const u16 l2 = f2bfu(v.z - bfu2f(h2)), l3 = f2bfu(v.w - bfu2f(h3));
        const int rt = r >> 4, kc = d0 >> 5;
        const int ln = (((d0 >> 3) & 3) << 4) | (r & 15);
        const int half = (d0 >> 2) & 1;
        u32* ph = (u32*)&AfH[rt][kc][ln];
        u32* pl = (u32*)&AfL[rt][kc][ln];
        ph[half * 2]     = (u32)h0 | ((u32)h1 << 16);
        ph[half * 2 + 1] = (u32)h2 | ((u32)h3 << 16);
        pl[half * 2]     = (u32)l0 | ((u32)l1 << 16);
        pl[half * 2 + 1] = (u32)l2 | ((u32)l3 << 16);
    }
    __syncthreads();

    const int l  = tid & 63;
    const int wv = tid >> 6;
    const int wr = wv >> 1, wc = wv & 1;

    f32x4 acc[2][8];
#pragma unroll
    for (int rt = 0; rt < 2; ++rt)
#pragma unroll
        for (int ct = 0; ct < 8; ++ct) {
            f32x4 z = {0.0f, 0.0f, 0.0f, 0.0f};
            acc[rt][ct] = z;
        }

#pragma unroll
    for (int kc = 0; kc < 4; ++kc) {
        bf16x8 aH[2], aL[2];
#pragma unroll
        for (int rt = 0; rt < 2; ++rt) {
            const uint4 uh = AfH[wr * 2 + rt][kc][l];
            const uint4 ul = AfL[wr * 2 + rt][kc][l];
            __builtin_memcpy(&aH[rt], &uh, 16);
            __builtin_memcpy(&aL[rt], &ul, 16);
        }
#pragma unroll
        for (int ct = 0; ct < 8; ++ct) {
            const uint4 uh = WPH[((wc * 4 + kc) * 8 + ct) * 64 + l];
            const uint4 ul = WPL[((wc * 4 + kc) * 8 + ct) * 64 + l];
            bf16x8 bH, bL;
            __builtin_memcpy(&bH, &uh, 16);
            __builtin_memcpy(&bL, &ul, 16);
#pragma unroll
            for (int rt = 0; rt < 2; ++rt) {
                acc[rt][ct] = __builtin_amdgcn_mfma_f32_16x16x32_bf16(aH[rt], bH, acc[rt][ct], 0, 0, 0);
                acc[rt][ct] = __builtin_amdgcn_mfma_f32_16x16x32_bf16(aL[rt], bH, acc[rt][ct], 0, 0, 0);
                acc[rt][ct] = __builtin_amdgcn_mfma_f32_16x16x32_bf16(aH[rt], bL, acc[rt][ct], 0, 0, 0);
            }
        }
    }

    float* outb = wc ? N1 : S1;
    const int cl  = l & 15;
    const int rq0 = (l >> 4) * 4;
#pragma unroll
    for (int rt = 0; rt < 2; ++rt)
#pragma unroll
        for (int q = 0; q < 4; ++q) {
            const size_t row = m0 + wr * 32 + rt * 16 + rq0 + q;
#pragma unroll
            for (int ct = 0; ct < 8; ++ct)
                outb[row * DD + ct * 16 + cl] = acc[rt][ct][q];
        }
}

// --------------- Kernel 3: sim = cosine similarity (fp32!) ---------------
__global__ __launch_bounds__(256)
void sim_kernel(const float* __restrict__ nodes, const float* __restrict__ inv_norm,
                float* __restrict__ sim)
{
    __shared__ float as[28][36];
    __shared__ float bs[NN][36];
    __shared__ float invs[NN];
    const int tid = threadIdx.x;
    const int b  = blockIdx.x / 7;
    const int n0 = (blockIdx.x % 7) * 28;
    const float* nb = nodes + (size_t)b * NN * DD;
    if (tid < NN) invs[tid] = inv_norm[b * NN + tid];
    const bool act = tid < 196;
    const int ai = act ? tid / 28 : 0;
    const int bi = act ? tid % 28 : 0;
    float acc[4][7];
#pragma unroll
    for (int r = 0; r < 4; ++r)
#pragma unroll
        for (int j = 0; j < 7; ++j) acc[r][j] = 0.0f;
    for (int dc = 0; dc < DD; dc += 32) {
        __syncthreads();
        if (tid < 224) {
            const int i = tid >> 3, q = tid & 7;
            *(float4*)(&as[i][q * 4]) = *(const float4*)(&nb[(size_t)(n0 + i) * DD + dc + q * 4]);
        }
        for (int idx = tid; idx < 1568; idx += 256) {
            const int r = idx >> 3, q = idx & 7;
            *(float4*)(&bs[r][q * 4]) = *(const float4*)(&nb[(size_t)r * DD + dc + q * 4]);
        }
        __syncthreads();
        if (act) {
            for (int dd = 0; dd < 32; dd += 4) {
                float4 a4[4], b4[7];
#pragma unroll
                for (int r = 0; r < 4; ++r) a4[r] = *(const float4*)(&as[ai * 4 + r][dd]);
#pragma unroll
                for (int j = 0; j < 7; ++j) b4[j] = *(const float4*)(&bs[bi * 7 + j][dd]);
#pragma unroll
                for (int r = 0; r < 4; ++r)
#pragma unroll
                    for (int j = 0; j < 7; ++j)
                        acc[r][j] += a4[r].x * b4[j].x + a4[r].y * b4[j].y
                                   + a4[r].z * b4[j].z + a4[r].w * b4[j].w;
            }
        }
    }
    if (act) {
#pragma unroll
        for (int r = 0; r < 4; ++r) {
            const int n = n0 + ai * 4 + r;
            const float sn = invs[n];
#pragma unroll
            for (int j = 0; j < 7; ++j) {
                const int m = bi * 7 + j;
                sim[((size_t)b * NN + n) * NN + m] = acc[r][j] * sn * invs[m];
            }
        }
    }
}

// --------------- Kernel 4: top-8, 4 rows/block (bit-identical math) ------
__global__ __launch_bounds__(256)
void topk_kernel(const float* __restrict__ sim, int* __restrict__ adj_i,
                 float* __restrict__ adj_o, const float* __restrict__ We2,
                 uint4* __restrict__ W2P)
{
    const int bid = blockIdx.x;
    if (bid >= (BB * NN) / 4) {
        const int e  = (bid - (BB * NN) / 4) * 256 + threadIdx.x;   // 0..2047
        const int l  = e & 63;
        const int fi = e >> 6;                 // ks*8 + ct
        const int ks = fi >> 3, ct = fi & 7;
        const int k0 = ks * 32 + (l >> 4) * 8;
        const int c  = ct * 16 + (l & 15);
        u16 v[8];
#pragma unroll
        for (int j = 0; j < 8; ++j) v[j] = f2bfu(We2[(size_t)(k0 + j) * DD + c]);
        uint4 pk;
        pk.x = (u32)v[0] | ((u32)v[1] << 16);
        pk.y = (u32)v[2] | ((u32)v[3] << 16);
        pk.z = (u32)v[4] | ((u32)v[5] << 16);
        pk.w = (u32)v[6] | ((u32)v[7] << 16);
        W2P[e] = pk;
        return;
    }
    const int bn = bid * 4 + (threadIdx.x >> 6);
    const int n = bn % NN;
    const int lane = threadIdx.x & 63;
    const float* srow = sim + (size_t)bn * NN;
    float v[4]; int mi[4];
#pragma unroll
    for (int s = 0; s < 4; ++s) {
        const int m = lane + 64 * s;
        mi[s] = m;
        v[s] = (m < NN && m != n) ? srow[m] : -3.0e38f;
    }
    for (int r = 0; r < KTOP; ++r) {
        float bv = v[0]; int bm = mi[0];
#pragma unroll
        for (int s = 1; s < 4; ++s) { if (v[s] > bv) { bv = v[s]; bm = mi[s]; } }
#pragma unroll
        for (int off = 32; off > 0; off >>= 1) {
            const float ov = __shfl_xor(bv, off);
            const int   om = __shfl_xor(bm, off);
            if (ov > bv || (ov == bv && om < bm)) { bv = ov; bm = om; }
        }
        if (lane == 0) {
            adj_i[bn * KTOP + r] = bm;
            adj_o[bn * KTOP + r] = (float)bm;
        }
#pragma unroll
        for (int s = 0; s < 4; ++s) if (mi[s] == bm) v[s] = -3.0e38f;
    }
}

// ------- Kernel 5: displacement table PC[729][D] = posmlp(d)@We1[256:384] --
__global__ __launch_bounds__(128)
void pos_kernel(const float* __restrict__ Wp1, const float* __restrict__ bp1,
                const float* __restrict__ Wp2, const float* __restrict__ bp2,
                const float* __restrict__ We1, float* __restrict__ PC)
{
    __shared__ float t1[64];
    __shared__ float sp[DD];
    const int e = blockIdx.x;
    const int dy = e / 27 - 13, dx = e % 27 - 13;
    const float fy = (float)dy / 13.0f, fx = (float)dx / 13.0f;
    const int tid = threadIdx.x;
    if (tid < 64) {
        const float h = fy * Wp1[tid] + fx * Wp1[64 + tid] + bp1[tid];
        t1[tid] = gelu_f(h);
    }
    __syncthreads();
    float s = bp2[tid];
    for (int j = 0; j < 64; ++j) s += t1[j] * Wp2[j * DD + tid];
    sp[tid] = s;
    __syncthreads();
    float o = 0.0f;
    for (int c = 0; c < DD; ++c) o += sp[c] * We1[(size_t)(256 + c) * DD + tid];
    PC[e * DD + tid] = o;
}

// -------- Kernel 6: edges = gelu(S1+N1g+PCg+be1) @ We2 + be2  (MFMA) -----
__global__ __launch_bounds__(256)
void edge_kernel(const float* __restrict__ S1, const float* __restrict__ N1,
                 const float* __restrict__ PC, const int* __restrict__ adj_i,
                 const float* __restrict__ be1, const uint4* __restrict__ W2P,
                 const float* __restrict__ be2, float* __restrict__ edges_o)
{
    __shared__ uint4 ldsB[2048];         // 32 KB: [frag(ks*8+ct)][lane] 16B
    const int tid = threadIdx.x;
    const int b  = blockIdx.x / 25;
    const int n0 = (blockIdx.x % 25) * 8;

#pragma unroll
    for (int p = 0; p < 8; ++p)
        ldsB[tid + 256 * p] = W2P[tid + 256 * p];

    const int l  = tid & 63;
    const int wv = tid >> 6;             // wave = row-tile index
    const int g  = l >> 4;               // k-group within 32-slice
    const int rA = wv * 16 + (l & 15);   // block-local edge row this lane feeds
    const int nA0 = n0 + (rA >> 3);
    const int nA  = (nA0 < NN) ? nA0 : 0;
    const int kA  = rA & 7;
    const int m   = adj_i[((size_t)b * NN + nA) * KTOP + kA];
    const int iy = nA / 14, ix = nA % 14;
    const int my = m / 14,  mx = m % 14;
    const int di = (my - iy + 13) * 27 + (mx - ix + 13);

    const float* s1r = S1 + ((size_t)b * NN + nA) * DD;
    const float* n1r = N1 + ((size_t)b * NN + m) * DD;
    const float* pcr = PC + (size_t)di * DD;

    bf16x8 afr[4];
#pragma unroll
    for (int ks = 0; ks < 4; ++ks) {
        const int k0 = ks * 32 + g * 8;
        float u[8];
#pragma unroll
        for (int h = 0; h < 2; ++h) {
            const int k = k0 + h * 4;
            const float4 s1 = *(const float4*)(s1r + k);
            const float4 n1 = *(const float4*)(n1r + k);
            const float4 pc = *(const float4*)(pcr + k);
            const float4 b1 = *(const float4*)(be1 + k);
            u[h * 4 + 0] = gelu_f(s1.x + n1.x + pc.x + b1.x);
            u[h * 4 + 1] = gelu_f(s1.y + n1.y + pc.y + b1.y);
            u[h * 4 + 2] = gelu_f(s1.z + n1.z + pc.z + b1.z);
            u[h * 4 + 3] = gelu_f(s1.w + n1.w + pc.w + b1.w);
        }
        bf16x8 a;
#pragma unroll
        for (int j = 0; j < 8; ++j) a[j] = (short)f2bfu(u[j]);
        afr[ks] = a;
    }
    __syncthreads();

    f32x4 acc[8];
#pragma unroll
    for (int ct = 0; ct < 8; ++ct) {
        f32x4 z = {0.0f, 0.0f, 0.0f, 0.0f};
        acc[ct] = z;
    }
#pragma unroll
    for (int ks = 0; ks < 4; ++ks) {
#pragma unroll
        for (int ct = 0; ct < 8; ++ct) {
            const uint4 bw = ldsB[(ks * 8 + ct) * 64 + l];
            bf16x8 bf; __builtin_memcpy(&bf, &bw, 16);
            acc[ct] = __builtin_amdgcn_mfma_f32_16x16x32_bf16(afr[ks], bf, acc[ct], 0, 0, 0);
        }
    }

    const int cl  = l & 15;
    const int rq0 = (l >> 4) * 4;
    float be2f[8];
#pragma unroll
    for (int ct = 0; ct < 8; ++ct) be2f[ct] = be2[ct * 16 + cl];
#pragma unroll
    for (int q = 0; q < 4; ++q) {
        const int r = wv * 16 + rq0 + q;       // block-local row
        const int n = n0 + (r >> 3);
        if (n < NN) {
            float* op = edges_o + (((size_t)b * NN + n) * KTOP + (r & 7)) * DD;
#pragma unroll
            for (int ct = 0; ct < 8; ++ct)
                op[ct * 16 + cl] = acc[ct][q] + be2f[ct];
        }
    }
}

extern "C" void kernel_launch(void* const* d_in, const int* in_sizes, int n_in,
                              void* d_out, int out_size, void* d_ws, size_t ws_size,
                              hipStream_t stream)
{
    const float* feat = (const float*)d_in[0];
    const float* Wn   = (const float*)d_in[1];
    const float* bn   = (const float*)d_in[2];
    const float* lng  = (const float*)d_in[3];
    const float* lnb  = (const float*)d_in[4];
    const float* Wp1  = (const float*)d_in[5];
    const float* bp1  = (const float*)d_in[6];
    const float* Wp2  = (const float*)d_in[7];
    const float* bp2  = (const float*)d_in[8];
    const float* We1  = (const float*)d_in[9];
    const float* be1  = (const float*)d_in[10];
    const float* We2  = (const float*)d_in[11];
    const float* be2  = (const float*)d_in[12];

    float* ws = (float*)d_ws;
    // part (6,422,528 floats) aliases [sim | head of S1] — dead before s1n1/sim run
    float* part     = ws;                    //  0 .. 6,422,528
    float* sim      = ws;                    //  4,917,248
    float* S1       = ws + 4917248;          //  3,211,264
    float* N1       = ws + 8128512;          //  3,211,264
    float* PC       = ws + 11339776;         //     93,312
    float* inv_norm = ws + 11433088;         //     25,088
    int*   adj_i    = (int*)(ws + 11458176); //    200,704 ints
    uint4* W2P      = (uint4*)(ws + 11433088);
    uint4* WPH      = (uint4*)(ws + 11339776);
    uint4* WPL      = WPH + 4096;

    float* out      = (float*)d_out;
    float* nodes    = out;                       // [B,N,D]   fp32
    float* edges_o  = out + 3211264;             // [B,N,K,D] fp32
    float* adj_o    = out + 3211264 + 25690112;  // [B,N,K]   fp32 (int values)

    pack_we1_kernel<<<16, 256, 0, stream>>>(We1, WPH, WPL);
    gemm_node_kernel<<<dim3(784, 2), 128, 0, stream>>>(feat, Wn, part);
    ln_kernel<<<3136, 128, 0, stream>>>(part, bn, lng, lnb, nodes, inv_norm);
    s1n1_kernel<<<392, 256, 0, stream>>>(nodes, WPH, WPL, S1, N1);
    pos_kernel<<<729, 128, 0, stream>>>(Wp1, bp1, Wp2, bp2, We1, PC);
    sim_kernel<<<BB * 7, 256, 0, stream>>>(nodes, inv_norm, sim);
    topk_kernel<<<(BB * NN) / 4 + 8, 256, 0, stream>>>(sim, adj_i, adj_o, We2, W2P);
    edge_kernel<<<BB * 25, 256, 0, stream>>>(S1, N1, PC, adj_i, be1, W2P, be2, edges_o);
}